// Round 1
// baseline (342.558 us; speedup 1.0000x reference)
//
#include <hip/hip_runtime.h>
#include <hip/hip_bf16.h>
#include <stdint.h>

#define B_DIM 64
#define S_DIM 512
#define K_DIM 1024   // F_IN
#define N_DIM 1024   // F_OUT
#define M_DIM (B_DIM * S_DIM)  // 32768

typedef __attribute__((ext_vector_type(8))) short short8;
typedef __attribute__((ext_vector_type(4))) float floatx4;

// ---------------------------------------------------------------------------
// Kernel 1: EMA scan along S on x (fp32) fused with fp32->bf16 convert.
// scan_S(x) @ W^T == scan_S(x @ W^T)  (linearity) -- so we scan the GEMM
// *input* and the GEMM then produces hiddens directly.
// One thread per (b, f_in): 64*1024 = 65536 threads, coalesced across f.
// ---------------------------------------------------------------------------
__global__ __launch_bounds__(256) void scan_x_kernel(
    const float* __restrict__ x, __hip_bfloat16* __restrict__ xs) {
  int t = blockIdx.x * 256 + threadIdx.x;   // 0..65535
  int b = t >> 10;
  int f = t & 1023;
  const float* px = x + (size_t)b * S_DIM * K_DIM + f;
  __hip_bfloat16* ps = xs + (size_t)b * S_DIM * K_DIM + f;
  float h = 0.0f;
  #pragma unroll 16
  for (int s = 0; s < S_DIM; ++s) {
    float v = px[(size_t)s * K_DIM];
    h = 0.5f * (h + v);                     // h = alpha*h + (1-alpha)*v, alpha=0.5
    ps[(size_t)s * K_DIM] = __float2bfloat16(h);
  }
}

// ---------------------------------------------------------------------------
// Kernel 2: W fp32 -> bf16 (tiny: 1M elements)
// ---------------------------------------------------------------------------
__global__ __launch_bounds__(256) void conv_w_kernel(
    const float* __restrict__ W, __hip_bfloat16* __restrict__ Wb) {
  int t = blockIdx.x * 256 + threadIdx.x;
  Wb[t] = __float2bfloat16(W[t]);
}

// ---------------------------------------------------------------------------
// Kernel 3: bf16 NT GEMM (m97-ladder structure): C[m,n] = sum_k A[m,k]*Bw[n,k]
// A = scanned x [M,K], Bw = W [N,K] (torch Linear layout == B^T, NT GEMM).
// 128x128 tile, BK=32, 4 waves of 64x64 (4x4 mfma_f32_16x16x32_bf16),
// global_load_lds width-16 staging. Epilogue writes hiddens to
// d_out+65536 and rows with s==511 also to hk (d_out[0:65536]).
// ---------------------------------------------------------------------------
__global__ __launch_bounds__(256) void gemm_kernel(
    const __hip_bfloat16* __restrict__ A,   // [M, K]
    const __hip_bfloat16* __restrict__ Bw,  // [N, K]
    float* __restrict__ out) {
  __shared__ __hip_bfloat16 lA[128 * 32];   // 8 KB
  __shared__ __hip_bfloat16 lB[128 * 32];   // 8 KB

  const int tid  = threadIdx.x;
  const int lane = tid & 63;
  const int w    = tid >> 6;        // wave 0..3
  const int wm   = (w >> 1) * 64;   // wave m offset within tile
  const int wn   = (w & 1) * 64;    // wave n offset within tile
  const int quad = lane >> 4;       // 0..3
  const int l15  = lane & 15;

  const int n0 = blockIdx.x * 128;
  const int m0 = blockIdx.y * 128;

  floatx4 acc[4][4] = {};

  for (int k0 = 0; k0 < K_DIM; k0 += 32) {
    // Stage A/B tiles. LDS dest must be wave-uniform-base + lane*16:
    // chunk c = tid + p*256 gives wave w, pass p the LDS range
    // [(p*4+w)*1024, +1024) with lane l at +l*16 -- exactly contiguous.
    #pragma unroll
    for (int p = 0; p < 2; ++p) {
      int c  = tid + p * 256;       // chunk 0..511 (16 B each)
      int r  = c >> 2;              // tile row 0..127
      int kc = (c & 3) * 8;         // bf16 col offset (8 elems = 16 B)
      const __hip_bfloat16* ga = A  + (size_t)(m0 + r) * K_DIM + k0 + kc;
      const __hip_bfloat16* gb = Bw + (size_t)(n0 + r) * K_DIM + k0 + kc;
      __builtin_amdgcn_global_load_lds(
          (const __attribute__((address_space(1))) void*)ga,
          (__attribute__((address_space(3))) void*)&lA[c * 8], 16, 0, 0);
      __builtin_amdgcn_global_load_lds(
          (const __attribute__((address_space(1))) void*)gb,
          (__attribute__((address_space(3))) void*)&lB[c * 8], 16, 0, 0);
    }
    __syncthreads();

    // Fragment loads: A[m=lane&15][k=quad*8+j] (ds_read_b128)
    short8 af[4], bfr[4];
    #pragma unroll
    for (int i = 0; i < 4; ++i) {
      af[i]  = *(const short8*)&lA[(wm + i * 16 + l15) * 32 + quad * 8];
      bfr[i] = *(const short8*)&lB[(wn + i * 16 + l15) * 32 + quad * 8];
    }
    #pragma unroll
    for (int i = 0; i < 4; ++i)
      #pragma unroll
      for (int j = 0; j < 4; ++j)
        acc[i][j] = __builtin_amdgcn_mfma_f32_16x16x32_bf16(
            af[i], bfr[j], acc[i][j], 0, 0, 0);
    __syncthreads();
  }

  // Epilogue: C/D layout col=lane&15 (n), row=quad*4+reg (m)  [m89-verified]
  float* hid = out + B_DIM * N_DIM;  // hiddens after hk (65536 floats)
  #pragma unroll
  for (int i = 0; i < 4; ++i) {
    #pragma unroll
    for (int j = 0; j < 4; ++j) {
      #pragma unroll
      for (int r = 0; r < 4; ++r) {
        int gm = m0 + wm + i * 16 + quad * 4 + r;
        int gn = n0 + wn + j * 16 + l15;
        float v = acc[i][j][r];
        hid[(size_t)gm * N_DIM + gn] = v;
        if ((gm & (S_DIM - 1)) == (S_DIM - 1)) {     // s == 511 -> hk row
          out[(size_t)(gm >> 9) * N_DIM + gn] = v;   // hk[b, n]
        }
      }
    }
  }
}

extern "C" void kernel_launch(void* const* d_in, const int* in_sizes, int n_in,
                              void* d_out, int out_size, void* d_ws, size_t ws_size,
                              hipStream_t stream) {
  const float* x = (const float*)d_in[0];   // [64, 512, 1024] fp32
  const float* W = (const float*)d_in[1];   // [1024, 1024] fp32
  float* out = (float*)d_out;               // [65536 hk][33.55M hiddens] fp32

  // Workspace layout: xs (scanned x, bf16, 64 MB) | Wb (bf16, 2 MB)
  __hip_bfloat16* xs = (__hip_bfloat16*)d_ws;
  __hip_bfloat16* Wb = (__hip_bfloat16*)((char*)d_ws + (size_t)M_DIM * K_DIM * 2);

  scan_x_kernel<<<dim3((B_DIM * K_DIM) / 256), dim3(256), 0, stream>>>(x, xs);
  conv_w_kernel<<<dim3((N_DIM * K_DIM) / 256), dim3(256), 0, stream>>>(W, Wb);
  gemm_kernel<<<dim3(N_DIM / 128, M_DIM / 128), dim3(256), 0, stream>>>(xs, Wb, out);
}